// Round 20
// baseline (147.451 us; speedup 1.0000x reference)
//
#include <hip/hip_runtime.h>
#include <math.h>

#define B_ 4
#define S_ 2048
#define E_ 512
#define H_ 8
#define Dh_ 64
#define BS_ (B_*S_)
#define MAXN 0.996f   // (1 - 4e-3)/sqrt(c), c=1

typedef __attribute__((ext_vector_type(8))) short short8;
typedef __attribute__((ext_vector_type(4))) float f32x4;

__device__ __forceinline__ unsigned f2bf(float x) {            // RNE f32->bf16 bits
  unsigned u = __float_as_uint(x);
  return (u + 0x7fffu + ((u >> 16) & 1u)) >> 16;
}
__device__ __forceinline__ float bf2f(unsigned b) {
  return __uint_as_float(b << 16);
}

__device__ __forceinline__ void gload_lds16(const void* g, void* lds) {
  __builtin_amdgcn_global_load_lds(
      (const __attribute__((address_space(1))) unsigned int*)g,
      (__attribute__((address_space(3))) unsigned int*)lds, 16, 0, 0);
}

// ---- pack W matrices: t-major B-frag order, HI ONLY
__global__ __launch_bounds__(256) void pack_w_kernel(const float* __restrict__ W0,
    const float* __restrict__ W1, const float* __restrict__ W2,
    const float* __restrict__ W3, unsigned short* __restrict__ Wp) {
  const float* W = (blockIdx.y == 0) ? W0 : (blockIdx.y == 1) ? W1
                 : (blockIdx.y == 2) ? W2 : W3;
  unsigned short* dst = Wp + (size_t)blockIdx.y * 262144;
  int l = threadIdx.x & 63, tq = threadIdx.x >> 6;
  int n = blockIdx.x;
  int col = 16*n + (l & 15);
  int k0 = 8 * (l >> 4);
  #pragma unroll
  for (int tt = 0; tt < 4; ++tt) {
    int t = tq*4 + tt;
    const float* wp_ = W + (size_t)col * E_ + 32*t + k0;
    float4 a0 = *(const float4*)wp_, a1 = *(const float4*)(wp_ + 4);
    float av[8] = {a0.x,a0.y,a0.z,a0.w,a1.x,a1.y,a1.z,a1.w};
    short8 hi;
    #pragma unroll
    for (int j = 0; j < 8; ++j) hi[j] = (short)f2bf(av[j]);
    *(short8*)(dst + ((size_t)(t*32 + n))*512 + l*8) = hi;
  }
}

// ---- pack X into A-frag bf16 hi/lo + fused row-stats.
__global__ __launch_bounds__(256) void pack_x_kernel(const float* __restrict__ X,
    unsigned short* __restrict__ Xp, float* __restrict__ xn_out,
    float* __restrict__ art_out) {
  __shared__ float sm[4][16];
  int R16 = blockIdx.x;
  int tid = threadIdx.x;
  int wv = tid >> 6, l = tid & 63;
  int l15 = l & 15;
  const float* xrow = X + (size_t)(R16*16 + l15)*E_ + 8*(l >> 4);
  float xsq = 0.f;
  #pragma unroll
  for (int tt = 0; tt < 4; ++tt) {
    int t = wv*4 + tt;
    float4 c0 = *(const float4*)(xrow + 32*t);
    float4 c1 = *(const float4*)(xrow + 32*t + 4);
    float av[8] = {c0.x,c0.y,c0.z,c0.w,c1.x,c1.y,c1.z,c1.w};
    short8 hi, lo;
    #pragma unroll
    for (int j = 0; j < 8; ++j) {
      unsigned hb = f2bf(av[j]);
      hi[j] = (short)hb;
      lo[j] = (short)f2bf(av[j] - bf2f(hb));
      xsq = fmaf(av[j], av[j], xsq);
    }
    unsigned short* o = Xp + ((size_t)(R16*16 + t)*2)*512 + l*8;
    *(short8*)o = hi;
    *(short8*)(o + 512) = lo;
  }
  xsq += __shfl_xor(xsq, 16, 64);
  xsq += __shfl_xor(xsq, 32, 64);
  if (l < 16) sm[wv][l] = xsq;
  __syncthreads();
  if (tid < 16) {
    float s = sm[0][tid] + sm[1][tid] + sm[2][tid] + sm[3][tid];
    float xnv = fmaxf(sqrtf(s), 1e-15f);
    float aa = fminf(xnv, 1.f - 1e-7f);
    xn_out[R16*16 + tid] = xnv;
    art_out[R16*16 + tid] = 0.5f * (log1pf(aa) - log1pf(-aa));
  }
}

// ---- QKV linears (r18): M=32, direct-L2 B-frags, pre-packed A, pure load->MFMA.
__global__ __launch_bounds__(256, 3) void qkv_linear(
    const unsigned short* __restrict__ Xp, const unsigned short* __restrict__ Wp,
    const float* __restrict__ bq_, const float* __restrict__ bk_,
    const float* __restrict__ bv_,
    unsigned short* __restrict__ Qhi, unsigned short* __restrict__ Khi,
    unsigned short* __restrict__ Vhi,
    const float* __restrict__ xn_arr, const float* __restrict__ art_arr,
    float* __restrict__ qn, float* __restrict__ kn, float* __restrict__ kni) {
  __shared__ float smM[2][4][4][4], smB[2][4][4][4], smb2[4];
  int tid = threadIdx.x;
  int w = tid >> 6, l = tid & 63;
  int l15 = l & 15, g = l >> 4;
  int R = blockIdx.x;
  int mat = blockIdx.y;
  const unsigned short* Wm = Wp + (size_t)mat * 262144;
  const float* bvec = (mat == 0) ? bq_ : (mat == 1) ? bk_ : bv_;
  unsigned short* outHi = (mat == 0) ? Qhi : (mat == 1) ? Khi : Vhi;
  float* normOut = (mat == 0) ? qn : kn;

  f32x4 acc0[8], acc1[8];
  #pragma unroll
  for (int s = 0; s < 8; ++s) {
    acc0[s] = (f32x4){0.f,0.f,0.f,0.f};
    acc1[s] = (f32x4){0.f,0.f,0.f,0.f};
  }
  const unsigned short* xp0 = Xp + ((size_t)(2*R)*16)*1024 + (size_t)l*8;
  const unsigned short* xp1 = Xp + ((size_t)(2*R+1)*16)*1024 + (size_t)l*8;
  const unsigned short* wl = Wm + (size_t)(8*w)*512 + (size_t)l*8;

  #pragma unroll 2
  for (int t = 0; t < 16; ++t) {
    const unsigned short* wb = wl + (size_t)t*16384;
    short8 b[8];
    #pragma unroll
    for (int s = 0; s < 8; ++s) b[s] = *(const short8*)(wb + s*512);
    short8 ahi0 = *(const short8*)(xp0 + t*1024);
    short8 alo0 = *(const short8*)(xp0 + t*1024 + 512);
    short8 ahi1 = *(const short8*)(xp1 + t*1024);
    short8 alo1 = *(const short8*)(xp1 + t*1024 + 512);
    #pragma unroll
    for (int s = 0; s < 8; ++s) {
      acc0[s] = __builtin_amdgcn_mfma_f32_16x16x32_bf16(ahi0, b[s], acc0[s], 0, 0, 0);
      acc0[s] = __builtin_amdgcn_mfma_f32_16x16x32_bf16(alo0, b[s], acc0[s], 0, 0, 0);
      acc1[s] = __builtin_amdgcn_mfma_f32_16x16x32_bf16(ahi1, b[s], acc1[s], 0, 0, 0);
      acc1[s] = __builtin_amdgcn_mfma_f32_16x16x32_bf16(alo1, b[s], acc1[s], 0, 0, 0);
    }
  }

  float xnv4[2][4], art4[2][4];
  #pragma unroll
  for (int rg = 0; rg < 2; ++rg)
    #pragma unroll
    for (int i = 0; i < 4; ++i) {
      int row = R*32 + rg*16 + 4*g + i;
      xnv4[rg][i] = xn_arr[row];
      art4[rg][i] = art_arr[row];
    }

  float bl[8];
  #pragma unroll
  for (int s = 0; s < 8; ++s) bl[s] = bvec[16*(8*w+s) + l15];
  float m2p[2][4] = {{0.f,0.f,0.f,0.f},{0.f,0.f,0.f,0.f}};
  float mbp[2][4] = {{0.f,0.f,0.f,0.f},{0.f,0.f,0.f,0.f}};
  float b2p = 0.f;
  #pragma unroll
  for (int s = 0; s < 8; ++s) {
    b2p += bl[s]*bl[s];
    #pragma unroll
    for (int i = 0; i < 4; ++i) {
      m2p[0][i] = fmaf(acc0[s][i], acc0[s][i], m2p[0][i]);
      mbp[0][i] = fmaf(acc0[s][i], bl[s], mbp[0][i]);
      m2p[1][i] = fmaf(acc1[s][i], acc1[s][i], m2p[1][i]);
      mbp[1][i] = fmaf(acc1[s][i], bl[s], mbp[1][i]);
    }
  }
  #pragma unroll
  for (int off = 1; off <= 8; off <<= 1) {
    b2p += __shfl_xor(b2p, off, 64);
    #pragma unroll
    for (int rg = 0; rg < 2; ++rg)
      #pragma unroll
      for (int i = 0; i < 4; ++i) {
        m2p[rg][i] += __shfl_xor(m2p[rg][i], off, 64);
        mbp[rg][i] += __shfl_xor(mbp[rg][i], off, 64);
      }
  }
  if (l == 0) smb2[w] = b2p;
  if (l15 == 0) {
    #pragma unroll
    for (int rg = 0; rg < 2; ++rg)
      #pragma unroll
      for (int i = 0; i < 4; ++i) { smM[rg][w][g][i] = m2p[rg][i]; smB[rg][w][g][i] = mbp[rg][i]; }
  }
  __syncthreads();
  float b2 = smb2[0] + smb2[1] + smb2[2] + smb2[3];
  float G[2][4], Hc[2][4];
  #pragma unroll
  for (int rg = 0; rg < 2; ++rg)
    #pragma unroll
    for (int i = 0; i < 4; ++i) {
      float m2 = smM[rg][0][g][i]+smM[rg][1][g][i]+smM[rg][2][g][i]+smM[rg][3][g][i];
      float mb = smB[rg][0][g][i]+smB[rg][1][g][i]+smB[rg][2][g][i]+smB[rg][3][g][i];
      float xn = xnv4[rg][i], art = art4[rg][i];
      float mn = fmaxf(sqrtf(m2), 1e-15f);
      float t = tanhf(mn / xn * art);
      float alpha, rn;
      if (m2 > 0.f) { alpha = t / mn; rn = t; } else { alpha = 0.f; rn = 0.f; }
      if (rn > MAXN) { alpha *= MAXN / rn; rn = MAXN; }        // project(res)
      float x2r = rn * rn;
      float xy = alpha * mb;
      float A  = 1.f + 2.f*xy + b2;
      float Bc = 1.f - x2r;
      float den = fmaxf(1.f + 2.f*xy + x2r*b2, 1e-15f);
      float n2v = (A*A*x2r + 2.f*A*Bc*xy + Bc*Bc*b2) / (den*den);
      float nn = fmaxf(sqrtf(n2v), 1e-15f);
      float sc = (nn > MAXN) ? (MAXN / nn) : 1.f;              // project(add)
      G[rg][i]  = sc * A * alpha / den;
      Hc[rg][i] = sc * Bc / den;
    }

  #pragma unroll
  for (int rg = 0; rg < 2; ++rg) {
    const f32x4* acc = rg ? acc1 : acc0;
    #pragma unroll
    for (int i = 0; i < 4; ++i) {
      int grow = R*32 + rg*16 + 4*g + i;
      int bb = grow >> 11, seq = grow & 2047;
      int tile = seq >> 6;
      float hn0 = 0.f, hn1 = 0.f;
      #pragma unroll
      for (int s = 0; s < 8; ++s) {
        int col = 16*(8*w+s) + l15;
        float v = G[rg][i]*acc[s][i] + Hc[rg][i]*bl[s];
        int h = col >> 6, c = col & 63;
        size_t base;
        if (mat == 2) {    // V layout
          int kt = (seq >> 5) & 1, gp = (seq >> 3) & 3, jv = seq & 7;
          int dn = c >> 4, lt = (c & 15) | (gp << 4);
          base = ((size_t)((bb*8 + h)*32 + tile))*4096 + (size_t)((kt*4+dn)*64 + lt)*8 + jv;
        } else {           // Q/K layout
          int nf = (seq >> 4) & 3, lt15 = seq & 15;
          int dt = c >> 5, m = (c >> 3) & 3, j = c & 7;
          base = ((size_t)((bb*8 + h)*32 + tile))*4096 + (size_t)((dt*4+nf)*64 + (lt15|(m<<4)))*8 + j;
        }
        outHi[base] = (unsigned short)f2bf(v);
        if (mat < 2) { if (s < 4) hn0 += v*v; else hn1 += v*v; }
      }
      if (mat < 2) {
        hn0 += __shfl_xor(hn0,1,64); hn0 += __shfl_xor(hn0,2,64);
        hn0 += __shfl_xor(hn0,4,64); hn0 += __shfl_xor(hn0,8,64);
        hn1 += __shfl_xor(hn1,1,64); hn1 += __shfl_xor(hn1,2,64);
        hn1 += __shfl_xor(hn1,4,64); hn1 += __shfl_xor(hn1,8,64);
        if (l15 == 0) {
          float h0 = fminf(hn0, 1.f - 1e-5f), h1 = fminf(hn1, 1.f - 1e-5f);
          size_t i0 = ((size_t)(bb*8 + 2*w + 0))*S_ + seq;
          size_t i1 = ((size_t)(bb*8 + 2*w + 1))*S_ + seq;
          normOut[i0] = h0;
          normOut[i1] = h1;
          if (mat == 1) {
            kni[i0] = 1.f / sqrtf(1.f - h0);
            kni[i1] = 1.f / sqrtf(1.f - h1);
          }
        }
      }
    }
  }
}

// ---- O-linear (r15-proven): M=32 direct-L2, in-loop convert, fp32 row output.
__global__ __launch_bounds__(256, 3) void o_linear(const float* __restrict__ X,
    const unsigned short* __restrict__ Wp, const float* __restrict__ bvec,
    float* __restrict__ outF) {
  __shared__ float smM[2][4][4][4], smB[2][4][4][4], smb2[4];
  int tid = threadIdx.x;
  int w = tid >> 6, l = tid & 63;
  int l15 = l & 15, g = l >> 4;
  int R = blockIdx.x;

  f32x4 acc0[8], acc1[8];
  #pragma unroll
  for (int s = 0; s < 8; ++s) {
    acc0[s] = (f32x4){0.f,0.f,0.f,0.f};
    acc1[s] = (f32x4){0.f,0.f,0.f,0.f};
  }
  const float* xrow0 = X + (size_t)(R*32 + l15)*E_ + 8*g;
  const float* xrow1 = xrow0 + (size_t)16*E_;
  const unsigned short* wl = Wp + (size_t)(8*w)*512 + (size_t)l*8;

  float4 p00 = *(const float4*)xrow0, p01 = *(const float4*)(xrow0 + 4);
  float4 p10 = *(const float4*)xrow1, p11 = *(const float4*)(xrow1 + 4);
  float xsq0 = 0.f, xsq1 = 0.f;

  #pragma unroll 1
  for (int t = 0; t < 16; ++t) {
    const unsigned short* wb = wl + (size_t)t*16384;
    short8 b[8];
    #pragma unroll
    for (int s = 0; s < 8; ++s) b[s] = *(const short8*)(wb + s*512);
    float a0v[8] = {p00.x,p00.y,p00.z,p00.w,p01.x,p01.y,p01.z,p01.w};
    float a1v[8] = {p10.x,p10.y,p10.z,p10.w,p11.x,p11.y,p11.z,p11.w};
    short8 ahi0, alo0, ahi1, alo1;
    #pragma unroll
    for (int j = 0; j < 8; ++j) {
      unsigned hb0 = f2bf(a0v[j]);
      ahi0[j] = (short)hb0;
      alo0[j] = (short)f2bf(a0v[j] - bf2f(hb0));
      xsq0 = fmaf(a0v[j], a0v[j], xsq0);
      unsigned hb1 = f2bf(a1v[j]);
      ahi1[j] = (short)hb1;
      alo1[j] = (short)f2bf(a1v[j] - bf2f(hb1));
      xsq1 = fmaf(a1v[j], a1v[j], xsq1);
    }
    if (t < 15) {
      p00 = *(const float4*)(xrow0 + 32*(t+1));
      p01 = *(const float4*)(xrow0 + 32*(t+1) + 4);
      p10 = *(const float4*)(xrow1 + 32*(t+1));
      p11 = *(const float4*)(xrow1 + 32*(t+1) + 4);
    }
    #pragma unroll
    for (int s = 0; s < 8; ++s) {
      acc0[s] = __builtin_amdgcn_mfma_f32_16x16x32_bf16(ahi0, b[s], acc0[s], 0, 0, 0);
      acc0[s] = __builtin_amdgcn_mfma_f32_16x16x32_bf16(alo0, b[s], acc0[s], 0, 0, 0);
      acc1[s] = __builtin_amdgcn_mfma_f32_16x16x32_bf16(ahi1, b[s], acc1[s], 0, 0, 0);
      acc1[s] = __builtin_amdgcn_mfma_f32_16x16x32_bf16(alo1, b[s], acc1[s], 0, 0, 0);
    }
  }

  xsq0 += __shfl_xor(xsq0, 16, 64); xsq0 += __shfl_xor(xsq0, 32, 64);
  xsq1 += __shfl_xor(xsq1, 16, 64); xsq1 += __shfl_xor(xsq1, 32, 64);
  float xnv4[2][4], art4[2][4];
  #pragma unroll
  for (int i = 0; i < 4; ++i) {
    float s20 = __shfl(xsq0, 4*g + i, 64);
    float s21 = __shfl(xsq1, 4*g + i, 64);
    float xn0 = fmaxf(sqrtf(s20), 1e-15f);
    float xn1 = fmaxf(sqrtf(s21), 1e-15f);
    float aa0 = fminf(xn0, 1.f - 1e-7f);
    float aa1 = fminf(xn1, 1.f - 1e-7f);
    xnv4[0][i] = xn0; art4[0][i] = 0.5f * (log1pf(aa0) - log1pf(-aa0));
    xnv4[1][i] = xn1; art4[1][i] = 0.5f * (log1pf(aa1) - log1pf(-aa1));
  }

  float bl[8];
  #pragma unroll
  for (int s = 0; s < 8; ++s) bl[s] = bvec[16*(8*w+s) + l15];
  float m2p[2][4] = {{0.f,0.f,0.f,0.f},{0.f,0.f,0.f,0.f}};
  float mbp[2][4] = {{0.f,0.f,0.f,0.f},{0.f,0.f,0.f,0.f}};
  float b2p = 0.f;
  #pragma unroll
  for (int s = 0; s < 8; ++s) {
    b2p += bl[s]*bl[s];
    #pragma unroll
    for (int i = 0; i < 4; ++i) {
      m2p[0][i] = fmaf(acc0[s][i], acc0[s][i], m2p[0][i]);
      mbp[0][i] = fmaf(acc0[s][i], bl[s], mbp[0][i]);
      m2p[1][i] = fmaf(acc1[s][i], acc1[s][i], m2p[1][i]);
      mbp[1][i] = fmaf(acc1[s][i], bl[s], mbp[1][i]);
    }
  }
  #pragma unroll
  for (int off = 1; off <= 8; off <<= 1) {
    b2p += __shfl_xor(b2p, off, 64);
    #pragma unroll
    for (int rg = 0; rg < 2; ++rg)
      #pragma unroll
      for (int i = 0; i < 4; ++i) {
        m2p[rg][i] += __shfl_xor(m2p[rg][i], off, 64);
        mbp[rg][i] += __shfl_xor(mbp[rg][i], off, 64);
      }
  }
  if (l == 0) smb2[w] = b2p;
  if (l15 == 0) {
    #pragma unroll
    for (int rg = 0; rg < 2; ++rg)
      #pragma unroll
      for (int i = 0; i < 4; ++i) { smM[rg][w][g][i] = m2p[rg][i]; smB[rg][w][g][i] = mbp[rg][i]; }
  }
  __syncthreads();
  float b2 = smb2[0] + smb2[1] + smb2[2] + smb2[3];
  #pragma unroll
  for (int rg = 0; rg < 2; ++rg) {
    const f32x4* acc = rg ? acc1 : acc0;
    #pragma unroll
    for (int i = 0; i < 4; ++i) {
      float m2 = smM[rg][0][g][i]+smM[rg][1][g][i]+smM[rg][2][g][i]+smM[rg][3][g][i];
      float mb = smB[rg][0][g][i]+smB[rg][1][g][i]+smB[rg][2][g][i]+smB[rg][3][g][i];
      float xn = xnv4[rg][i], art = art4[rg][i];
      float mn = fmaxf(sqrtf(m2), 1e-15f);
      float t = tanhf(mn / xn * art);
      float alpha, rn;
      if (m2 > 0.f) { alpha = t / mn; rn = t; } else { alpha = 0.f; rn = 0.f; }
      if (rn > MAXN) { alpha *= MAXN / rn; rn = MAXN; }
      float x2r = rn * rn;
      float xy = alpha * mb;
      float A  = 1.f + 2.f*xy + b2;
      float Bc = 1.f - x2r;
      float den = fmaxf(1.f + 2.f*xy + x2r*b2, 1e-15f);
      float n2v = (A*A*x2r + 2.f*A*Bc*xy + Bc*Bc*b2) / (den*den);
      float nn = fmaxf(sqrtf(n2v), 1e-15f);
      float sc = (nn > MAXN) ? (MAXN / nn) : 1.f;
      float Gv = sc * A * alpha / den;
      float Hv = sc * Bc / den;
      int grow = R*32 + rg*16 + 4*g + i;
      #pragma unroll
      for (int s = 0; s < 8; ++s)
        outF[(size_t)grow*E_ + 16*(8*w+s) + l15] = Gv*acc[s][i] + Hv*bl[s];
    }
  }
}

// ---- Attention v11: 2 row-groups per wave (128 q-rows/block) — each K/V
// ds_read feeds 2 MFMAs; barriers per q-row halve. 48KB LDS, grid 512.
__global__ __launch_bounds__(256, 2) void attn_kernel(
    const unsigned short* __restrict__ Qhi, const unsigned short* __restrict__ Khi,
    const unsigned short* __restrict__ Vhi,
    const float* __restrict__ qn_arr, const float* __restrict__ kn_arr,
    const float* __restrict__ kni_arr, float* __restrict__ Out) {
  __shared__ __align__(16) unsigned short Kf[2][4096];
  __shared__ __align__(16) unsigned short Vf[2][4096];
  __shared__ __align__(16) unsigned short Pf[4][2][1024];   // 48KB total

  int tid = threadIdx.x;
  int w = tid >> 6, l = tid & 63;
  int l15 = l & 15, g = l >> 4;

  int bid = blockIdx.x;                 // 512 blocks; xcd owns bh 4*xcd..4*xcd+3
  int xcd = bid & 7, idx = bid >> 3;    // idx 0..63
  int bh = xcd * 4 + (idx >> 4);
  int qblk = idx & 15;                  // 128-row block
  int b = bh >> 3, h = bh & 7;
  int qb = qblk * 128;

  // Q frags for both row groups: rows qb + w*32 + rg*16 + [0,16)
  short8 qhi[2][2];
  float qnv[2][4], pr[2][4];
  #pragma unroll
  for (int rg = 0; rg < 2; ++rg) {
    int rw = 2*w + rg;                  // 16-row unit index within 128
    int qtile = qblk*2 + (rw >> 2);
    int nf = rw & 3;
    const unsigned short* qbase = Qhi + ((size_t)(bh*32 + qtile))*4096;
    #pragma unroll
    for (int dt = 0; dt < 2; ++dt)
      qhi[rg][dt] = *(const short8*)(qbase + (size_t)((dt*4 + nf)*64 + l)*8);
    #pragma unroll
    for (int i = 0; i < 4; ++i) {
      qnv[rg][i] = qn_arr[(size_t)bh*S_ + qb + rw*16 + 4*g + i];
      pr[rg][i] = -0.25503386f * __builtin_amdgcn_rsqf(1.f - qnv[rg][i]);
    }
  }

  f32x4 Oacc[2][4];
  float lp[2][4];
  #pragma unroll
  for (int rg = 0; rg < 2; ++rg)
    #pragma unroll
    for (int dn = 0; dn < 4; ++dn) {
      Oacc[rg][dn] = (f32x4){0.f,0.f,0.f,0.f};
      lp[rg][dn] = 0.f;
    }

  const unsigned short* Kbh = Khi + ((size_t)bh*32)*4096;
  const unsigned short* Vbh = Vhi + ((size_t)bh*32)*4096;
  const float* knp  = kn_arr  + (size_t)bh*S_;
  const float* knip = kni_arr + (size_t)bh*S_;

  #pragma unroll
  for (int r = 0; r < 2; ++r) {
    gload_lds16(Kbh + r*2048 + w*512 + l*8, &Kf[0][r*2048 + w*512]);
    gload_lds16(Vbh + r*2048 + w*512 + l*8, &Vf[0][r*2048 + w*512]);
  }
  asm volatile("s_waitcnt vmcnt(0)" ::: "memory");
  __syncthreads();

  #pragma unroll 1
  for (int tile = 0; tile < 32; ++tile) {
    int cur = tile & 1;
    int kb = tile * 64;
    float knc[4], kin[4];
    #pragma unroll
    for (int n = 0; n < 4; ++n) {       // issued first -> retire before stages
      knc[n] = knp[kb + 16*n + l15];
      kin[n] = knip[kb + 16*n + l15];
    }
    if (tile < 31) {
      const unsigned short* kp = Kbh + ((size_t)(tile+1))*4096;
      const unsigned short* vp = Vbh + ((size_t)(tile+1))*4096;
      #pragma unroll
      for (int r = 0; r < 2; ++r) {
        gload_lds16(kp + r*2048 + w*512 + l*8, &Kf[cur^1][r*2048 + w*512]);
        gload_lds16(vp + r*2048 + w*512 + l*8, &Vf[cur^1][r*2048 + w*512]);
      }
    }
    __builtin_amdgcn_sched_barrier(0);
    // ---- QK^T + softmax + P store (K frag read once, used by both rgs)
    #pragma unroll
    for (int n = 0; n < 4; ++n) {
      f32x4 C0 = (f32x4){0.f,0.f,0.f,0.f};
      f32x4 C1 = (f32x4){0.f,0.f,0.f,0.f};
      #pragma unroll
      for (int dt = 0; dt < 2; ++dt) {
        short8 kfr = *(const short8*)&Kf[cur][((dt*4 + n)*64 + l)*8];
        C0 = __builtin_amdgcn_mfma_f32_16x16x32_bf16(qhi[0][dt], kfr, C0, 0, 0, 0);
        C1 = __builtin_amdgcn_mfma_f32_16x16x32_bf16(qhi[1][dt], kfr, C1, 0, 0, 0);
      }
      int cbase = (n >> 1)*64 + 16*((2*n + (l15 >> 3)) & 3) + 4*g;
      int csb = cbase ^ ((cbase >> 3) & 7);
      int j7 = l15 & 7;
      #pragma unroll
      for (int i = 0; i < 4; ++i) {
        float num0 = fmaf(-qnv[0][i], knc[n], C0[i]);
        float d20 = fmaxf(num0, 5e-6f);
        float sq0 = d20 * __builtin_amdgcn_rsqf(d20);
        float p0 = __builtin_amdgcn_exp2f(pr[0][i] * kin[n] * sq0);
        unsigned u0 = __float_as_uint(p0);
        lp[0][i] += __uint_as_float(u0 & 0xffff0000u);
        Pf[w][0][((csb ^ i) << 3) + j7] = (unsigned short)(u0 >> 16);
        float num1 = fmaf(-qnv[1][i], knc[n], C1[i]);
        float d21 = fmaxf(num1, 5e-6f);
        float sq1 = d21 * __builtin_amdgcn_rsqf(d21);
        float p1 = __builtin_amdgcn_exp2f(pr[1][i] * kin[n] * sq1);
        unsigned u1 = __float_as_uint(p1);
        lp[1][i] += __uint_as_float(u1 & 0xffff0000u);
        Pf[w][1][((csb ^ i) << 3) + j7] = (unsigned short)(u1 >> 16);
      }
    }
    // ---- PV (V frag read once, used by both rgs)
    short8 pa[2][2];
    #pragma unroll
    for (int rg = 0; rg < 2; ++rg) {
      { int c = l;      int cs = c ^ ((c >> 3) & 7); pa[rg][0] = *(const short8*)&Pf[w][rg][cs*8]; }
      { int c = 64 + l; int cs = c ^ ((c >> 3) & 7); pa[rg][1] = *(const short8*)&Pf[w][rg][cs*8]; }
    }
    #pragma unroll
    for (int dn = 0; dn < 4; ++dn) {
      short8 v0 = *(const short8*)&Vf[cur][((0*4 + dn)*64 + l)*8];
      short8 v1 = *(const short8*)&Vf[cur][((1*4 + dn)*64 + l)*8];
      #pragma unroll
      for (int rg = 0; rg < 2; ++rg) {
        f32x4 o = Oacc[rg][dn];
        o = __builtin_amdgcn_mfma_f32_16x16x32_bf16(pa[rg][0], v0, o, 0, 0, 0);
        o = __builtin_amdgcn_mfma_f32_16x16x32_bf16(pa[rg][1], v1, o, 0, 0, 0);
        Oacc[rg][dn] = o;
      }
    }
    asm volatile("s_waitcnt vmcnt(0)" ::: "memory");
    __builtin_amdgcn_s_barrier();
  }

  #pragma unroll
  for (int rg = 0; rg < 2; ++rg) {
    #pragma unroll
    for (int i = 0; i < 4; ++i) {
      lp[rg][i] += __shfl_xor(lp[rg][i], 1, 64);
      lp[rg][i] += __shfl_xor(lp[rg][i], 2, 64);
      lp[rg][i] += __shfl_xor(lp[rg][i], 4, 64);
      lp[rg][i] += __shfl_xor(lp[rg][i], 8, 64);
      lp[rg][i] = 1.f / lp[rg][i];
    }
    #pragma unroll
    for (int i = 0; i < 4; ++i) {
      size_t orow = (size_t)(b*S_ + qb + (2*w+rg)*16 + 4*g + i)*E_ + h*Dh_;
      #pragma unroll
      for (int dn = 0; dn < 4; ++dn)
        Out[orow + 16*dn + l15] = Oacc[rg][dn][i] * lp[rg][i];
    }
  }
}

extern "C" void kernel_launch(void* const* d_in, const int* in_sizes, int n_in,
                              void* d_out, int out_size, void* d_ws, size_t ws_size,
                              hipStream_t stream) {
  const float* x  = (const float*)d_in[0];
  const float* Wq = (const float*)d_in[1];
  const float* bq = (const float*)d_in[2];
  const float* Wk = (const float*)d_in[3];
  const float* bk = (const float*)d_in[4];
  const float* Wv = (const float*)d_in[5];
  const float* bv = (const float*)d_in[6];
  const float* Wo = (const float*)d_in[7];
  const float* bo = (const float*)d_in[8];
  float* out = (float*)d_out;

  char* p = (char*)d_ws;
  unsigned short* Wp  = (unsigned short*)p; p += (size_t)2  << 20;  // 2 MB (hi only)
  unsigned short* Xp  = (unsigned short*)p; p += (size_t)17 << 20;  // 16.8 MB (hi+lo)
  unsigned short* Qhi = (unsigned short*)p; p += (size_t)8  << 20;
  unsigned short* Khi = (unsigned short*)p; p += (size_t)8  << 20;
  unsigned short* Vhi = (unsigned short*)p; p += (size_t)8  << 20;
  float* ao   = (float*)p; p += (size_t)16 << 20;                   // attn out fp32
  float* xn   = (float*)p; p += BS_ * 4;
  float* art  = (float*)p; p += BS_ * 4;
  float* qn   = (float*)p; p += (size_t)B_*H_*S_ * 4;
  float* kn   = (float*)p; p += (size_t)B_*H_*S_ * 4;
  float* kni  = (float*)p; p += (size_t)B_*H_*S_ * 4;
  // total ~= 60 MB

  pack_w_kernel<<<dim3(32, 4), dim3(256), 0, stream>>>(Wq, Wk, Wv, Wo, Wp);
  pack_x_kernel<<<dim3(BS_/16), dim3(256), 0, stream>>>(x, Xp, xn, art);
  qkv_linear<<<dim3(BS_/32, 3), dim3(256), 0, stream>>>(Xp, Wp, bq, bk, bv,
                                                        Qhi, Khi, Vhi, xn, art, qn, kn, kni);
  attn_kernel<<<dim3(512), dim3(256), 0, stream>>>(Qhi, Khi, Vhi, qn, kn, kni, ao);
  o_linear<<<dim3(BS_/32), dim3(256), 0, stream>>>(ao, Wp + 3*262144, bo, out);
}

// Round 21
// 141.589 us; speedup vs baseline: 1.0414x; 1.0414x over previous
//
#include <hip/hip_runtime.h>
#include <math.h>

#define B_ 4
#define S_ 2048
#define E_ 512
#define H_ 8
#define Dh_ 64
#define BS_ (B_*S_)
#define MAXN 0.996f   // (1 - 4e-3)/sqrt(c), c=1

typedef __attribute__((ext_vector_type(8))) short short8;
typedef __attribute__((ext_vector_type(4))) float f32x4;

__device__ __forceinline__ unsigned f2bf(float x) {            // RNE f32->bf16 bits
  unsigned u = __float_as_uint(x);
  return (u + 0x7fffu + ((u >> 16) & 1u)) >> 16;
}
__device__ __forceinline__ float bf2f(unsigned b) {
  return __uint_as_float(b << 16);
}

__device__ __forceinline__ void gload_lds16(const void* g, void* lds) {
  __builtin_amdgcn_global_load_lds(
      (const __attribute__((address_space(1))) unsigned int*)g,
      (__attribute__((address_space(3))) unsigned int*)lds, 16, 0, 0);
}

// ---- fused pack: blocks 0..127 pack W (hi-only, t-major B-frag order);
// blocks 128..639 pack X (A-frag hi/lo) + fused row-stats.
__global__ __launch_bounds__(256) void pack_wx_kernel(
    const float* __restrict__ W0, const float* __restrict__ W1,
    const float* __restrict__ W2, const float* __restrict__ W3,
    unsigned short* __restrict__ Wp,
    const float* __restrict__ X, unsigned short* __restrict__ Xp,
    float* __restrict__ xn_out, float* __restrict__ art_out) {
  __shared__ float sm[4][16];
  int bid = blockIdx.x;
  if (bid < 128) {
    // ---- pack_w: mat = bid>>5, n = bid&31
    int mat = bid >> 5, n = bid & 31;
    const float* W = (mat == 0) ? W0 : (mat == 1) ? W1 : (mat == 2) ? W2 : W3;
    unsigned short* dst = Wp + (size_t)mat * 262144;
    int l = threadIdx.x & 63, tq = threadIdx.x >> 6;
    int col = 16*n + (l & 15);
    int k0 = 8 * (l >> 4);
    #pragma unroll
    for (int tt = 0; tt < 4; ++tt) {
      int t = tq*4 + tt;
      const float* wp_ = W + (size_t)col * E_ + 32*t + k0;
      float4 a0 = *(const float4*)wp_, a1 = *(const float4*)(wp_ + 4);
      float av[8] = {a0.x,a0.y,a0.z,a0.w,a1.x,a1.y,a1.z,a1.w};
      short8 hi;
      #pragma unroll
      for (int j = 0; j < 8; ++j) hi[j] = (short)f2bf(av[j]);
      *(short8*)(dst + ((size_t)(t*32 + n))*512 + l*8) = hi;
    }
  } else {
    // ---- pack_x: R16 = bid-128
    int R16 = bid - 128;
    int tid = threadIdx.x;
    int wv = tid >> 6, l = tid & 63;
    int l15 = l & 15;
    const float* xrow = X + (size_t)(R16*16 + l15)*E_ + 8*(l >> 4);
    float xsq = 0.f;
    #pragma unroll
    for (int tt = 0; tt < 4; ++tt) {
      int t = wv*4 + tt;
      float4 c0 = *(const float4*)(xrow + 32*t);
      float4 c1 = *(const float4*)(xrow + 32*t + 4);
      float av[8] = {c0.x,c0.y,c0.z,c0.w,c1.x,c1.y,c1.z,c1.w};
      short8 hi, lo;
      #pragma unroll
      for (int j = 0; j < 8; ++j) {
        unsigned hb = f2bf(av[j]);
        hi[j] = (short)hb;
        lo[j] = (short)f2bf(av[j] - bf2f(hb));
        xsq = fmaf(av[j], av[j], xsq);
      }
      unsigned short* o = Xp + ((size_t)(R16*16 + t)*2)*512 + l*8;
      *(short8*)o = hi;
      *(short8*)(o + 512) = lo;
    }
    xsq += __shfl_xor(xsq, 16, 64);
    xsq += __shfl_xor(xsq, 32, 64);
    if (l < 16) sm[wv][l] = xsq;
    __syncthreads();
    if (tid < 16) {
      float s = sm[0][tid] + sm[1][tid] + sm[2][tid] + sm[3][tid];
      float xnv = fmaxf(sqrtf(s), 1e-15f);
      float aa = fminf(xnv, 1.f - 1e-7f);
      xn_out[R16*16 + tid] = xnv;
      art_out[R16*16 + tid] = 0.5f * (log1pf(aa) - log1pf(-aa));
    }
  }
}

// ---- QKV linears (r18-proven): M=32, direct-L2 B-frags, pre-packed A.
__global__ __launch_bounds__(256, 3) void qkv_linear(
    const unsigned short* __restrict__ Xp, const unsigned short* __restrict__ Wp,
    const float* __restrict__ bq_, const float* __restrict__ bk_,
    const float* __restrict__ bv_,
    unsigned short* __restrict__ Qhi, unsigned short* __restrict__ Khi,
    unsigned short* __restrict__ Vhi,
    const float* __restrict__ xn_arr, const float* __restrict__ art_arr,
    float* __restrict__ qn, float* __restrict__ kn, float* __restrict__ kni) {
  __shared__ float smM[2][4][4][4], smB[2][4][4][4], smb2[4];
  int tid = threadIdx.x;
  int w = tid >> 6, l = tid & 63;
  int l15 = l & 15, g = l >> 4;
  int R = blockIdx.x;
  int mat = blockIdx.y;
  const unsigned short* Wm = Wp + (size_t)mat * 262144;
  const float* bvec = (mat == 0) ? bq_ : (mat == 1) ? bk_ : bv_;
  unsigned short* outHi = (mat == 0) ? Qhi : (mat == 1) ? Khi : Vhi;
  float* normOut = (mat == 0) ? qn : kn;

  f32x4 acc0[8], acc1[8];
  #pragma unroll
  for (int s = 0; s < 8; ++s) {
    acc0[s] = (f32x4){0.f,0.f,0.f,0.f};
    acc1[s] = (f32x4){0.f,0.f,0.f,0.f};
  }
  const unsigned short* xp0 = Xp + ((size_t)(2*R)*16)*1024 + (size_t)l*8;
  const unsigned short* xp1 = Xp + ((size_t)(2*R+1)*16)*1024 + (size_t)l*8;
  const unsigned short* wl = Wm + (size_t)(8*w)*512 + (size_t)l*8;

  #pragma unroll 2
  for (int t = 0; t < 16; ++t) {
    const unsigned short* wb = wl + (size_t)t*16384;
    short8 b[8];
    #pragma unroll
    for (int s = 0; s < 8; ++s) b[s] = *(const short8*)(wb + s*512);
    short8 ahi0 = *(const short8*)(xp0 + t*1024);
    short8 alo0 = *(const short8*)(xp0 + t*1024 + 512);
    short8 ahi1 = *(const short8*)(xp1 + t*1024);
    short8 alo1 = *(const short8*)(xp1 + t*1024 + 512);
    #pragma unroll
    for (int s = 0; s < 8; ++s) {
      acc0[s] = __builtin_amdgcn_mfma_f32_16x16x32_bf16(ahi0, b[s], acc0[s], 0, 0, 0);
      acc0[s] = __builtin_amdgcn_mfma_f32_16x16x32_bf16(alo0, b[s], acc0[s], 0, 0, 0);
      acc1[s] = __builtin_amdgcn_mfma_f32_16x16x32_bf16(ahi1, b[s], acc1[s], 0, 0, 0);
      acc1[s] = __builtin_amdgcn_mfma_f32_16x16x32_bf16(alo1, b[s], acc1[s], 0, 0, 0);
    }
  }

  float xnv4[2][4], art4[2][4];
  #pragma unroll
  for (int rg = 0; rg < 2; ++rg)
    #pragma unroll
    for (int i = 0; i < 4; ++i) {
      int row = R*32 + rg*16 + 4*g + i;
      xnv4[rg][i] = xn_arr[row];
      art4[rg][i] = art_arr[row];
    }

  float bl[8];
  #pragma unroll
  for (int s = 0; s < 8; ++s) bl[s] = bvec[16*(8*w+s) + l15];
  float m2p[2][4] = {{0.f,0.f,0.f,0.f},{0.f,0.f,0.f,0.f}};
  float mbp[2][4] = {{0.f,0.f,0.f,0.f},{0.f,0.f,0.f,0.f}};
  float b2p = 0.f;
  #pragma unroll
  for (int s = 0; s < 8; ++s) {
    b2p += bl[s]*bl[s];
    #pragma unroll
    for (int i = 0; i < 4; ++i) {
      m2p[0][i] = fmaf(acc0[s][i], acc0[s][i], m2p[0][i]);
      mbp[0][i] = fmaf(acc0[s][i], bl[s], mbp[0][i]);
      m2p[1][i] = fmaf(acc1[s][i], acc1[s][i], m2p[1][i]);
      mbp[1][i] = fmaf(acc1[s][i], bl[s], mbp[1][i]);
    }
  }
  #pragma unroll
  for (int off = 1; off <= 8; off <<= 1) {
    b2p += __shfl_xor(b2p, off, 64);
    #pragma unroll
    for (int rg = 0; rg < 2; ++rg)
      #pragma unroll
      for (int i = 0; i < 4; ++i) {
        m2p[rg][i] += __shfl_xor(m2p[rg][i], off, 64);
        mbp[rg][i] += __shfl_xor(mbp[rg][i], off, 64);
      }
  }
  if (l == 0) smb2[w] = b2p;
  if (l15 == 0) {
    #pragma unroll
    for (int rg = 0; rg < 2; ++rg)
      #pragma unroll
      for (int i = 0; i < 4; ++i) { smM[rg][w][g][i] = m2p[rg][i]; smB[rg][w][g][i] = mbp[rg][i]; }
  }
  __syncthreads();
  float b2 = smb2[0] + smb2[1] + smb2[2] + smb2[3];
  float G[2][4], Hc[2][4];
  #pragma unroll
  for (int rg = 0; rg < 2; ++rg)
    #pragma unroll
    for (int i = 0; i < 4; ++i) {
      float m2 = smM[rg][0][g][i]+smM[rg][1][g][i]+smM[rg][2][g][i]+smM[rg][3][g][i];
      float mb = smB[rg][0][g][i]+smB[rg][1][g][i]+smB[rg][2][g][i]+smB[rg][3][g][i];
      float xn = xnv4[rg][i], art = art4[rg][i];
      float mn = fmaxf(sqrtf(m2), 1e-15f);
      float t = tanhf(mn / xn * art);
      float alpha, rn;
      if (m2 > 0.f) { alpha = t / mn; rn = t; } else { alpha = 0.f; rn = 0.f; }
      if (rn > MAXN) { alpha *= MAXN / rn; rn = MAXN; }        // project(res)
      float x2r = rn * rn;
      float xy = alpha * mb;
      float A  = 1.f + 2.f*xy + b2;
      float Bc = 1.f - x2r;
      float den = fmaxf(1.f + 2.f*xy + x2r*b2, 1e-15f);
      float n2v = (A*A*x2r + 2.f*A*Bc*xy + Bc*Bc*b2) / (den*den);
      float nn = fmaxf(sqrtf(n2v), 1e-15f);
      float sc = (nn > MAXN) ? (MAXN / nn) : 1.f;              // project(add)
      G[rg][i]  = sc * A * alpha / den;
      Hc[rg][i] = sc * Bc / den;
    }

  #pragma unroll
  for (int rg = 0; rg < 2; ++rg) {
    const f32x4* acc = rg ? acc1 : acc0;
    #pragma unroll
    for (int i = 0; i < 4; ++i) {
      int grow = R*32 + rg*16 + 4*g + i;
      int bb = grow >> 11, seq = grow & 2047;
      int tile = seq >> 6;
      float hn0 = 0.f, hn1 = 0.f;
      #pragma unroll
      for (int s = 0; s < 8; ++s) {
        int col = 16*(8*w+s) + l15;
        float v = G[rg][i]*acc[s][i] + Hc[rg][i]*bl[s];
        int h = col >> 6, c = col & 63;
        size_t base;
        if (mat == 2) {    // V layout
          int kt = (seq >> 5) & 1, gp = (seq >> 3) & 3, jv = seq & 7;
          int dn = c >> 4, lt = (c & 15) | (gp << 4);
          base = ((size_t)((bb*8 + h)*32 + tile))*4096 + (size_t)((kt*4+dn)*64 + lt)*8 + jv;
        } else {           // Q/K layout
          int nf = (seq >> 4) & 3, lt15 = seq & 15;
          int dt = c >> 5, m = (c >> 3) & 3, j = c & 7;
          base = ((size_t)((bb*8 + h)*32 + tile))*4096 + (size_t)((dt*4+nf)*64 + (lt15|(m<<4)))*8 + j;
        }
        outHi[base] = (unsigned short)f2bf(v);
        if (mat < 2) { if (s < 4) hn0 += v*v; else hn1 += v*v; }
      }
      if (mat < 2) {
        hn0 += __shfl_xor(hn0,1,64); hn0 += __shfl_xor(hn0,2,64);
        hn0 += __shfl_xor(hn0,4,64); hn0 += __shfl_xor(hn0,8,64);
        hn1 += __shfl_xor(hn1,1,64); hn1 += __shfl_xor(hn1,2,64);
        hn1 += __shfl_xor(hn1,4,64); hn1 += __shfl_xor(hn1,8,64);
        if (l15 == 0) {
          float h0 = fminf(hn0, 1.f - 1e-5f), h1 = fminf(hn1, 1.f - 1e-5f);
          size_t i0 = ((size_t)(bb*8 + 2*w + 0))*S_ + seq;
          size_t i1 = ((size_t)(bb*8 + 2*w + 1))*S_ + seq;
          normOut[i0] = h0;
          normOut[i1] = h1;
          if (mat == 1) {
            kni[i0] = 1.f / sqrtf(1.f - h0);
            kni[i1] = 1.f / sqrtf(1.f - h1);
          }
        }
      }
    }
  }
}

// ---- O-linear (r15-proven): M=32 direct-L2, in-loop convert, fp32 row output.
__global__ __launch_bounds__(256, 3) void o_linear(const float* __restrict__ X,
    const unsigned short* __restrict__ Wp, const float* __restrict__ bvec,
    float* __restrict__ outF) {
  __shared__ float smM[2][4][4][4], smB[2][4][4][4], smb2[4];
  int tid = threadIdx.x;
  int w = tid >> 6, l = tid & 63;
  int l15 = l & 15, g = l >> 4;
  int R = blockIdx.x;

  f32x4 acc0[8], acc1[8];
  #pragma unroll
  for (int s = 0; s < 8; ++s) {
    acc0[s] = (f32x4){0.f,0.f,0.f,0.f};
    acc1[s] = (f32x4){0.f,0.f,0.f,0.f};
  }
  const float* xrow0 = X + (size_t)(R*32 + l15)*E_ + 8*g;
  const float* xrow1 = xrow0 + (size_t)16*E_;
  const unsigned short* wl = Wp + (size_t)(8*w)*512 + (size_t)l*8;

  float4 p00 = *(const float4*)xrow0, p01 = *(const float4*)(xrow0 + 4);
  float4 p10 = *(const float4*)xrow1, p11 = *(const float4*)(xrow1 + 4);
  float xsq0 = 0.f, xsq1 = 0.f;

  #pragma unroll 1
  for (int t = 0; t < 16; ++t) {
    const unsigned short* wb = wl + (size_t)t*16384;
    short8 b[8];
    #pragma unroll
    for (int s = 0; s < 8; ++s) b[s] = *(const short8*)(wb + s*512);
    float a0v[8] = {p00.x,p00.y,p00.z,p00.w,p01.x,p01.y,p01.z,p01.w};
    float a1v[8] = {p10.x,p10.y,p10.z,p10.w,p11.x,p11.y,p11.z,p11.w};
    short8 ahi0, alo0, ahi1, alo1;
    #pragma unroll
    for (int j = 0; j < 8; ++j) {
      unsigned hb0 = f2bf(a0v[j]);
      ahi0[j] = (short)hb0;
      alo0[j] = (short)f2bf(a0v[j] - bf2f(hb0));
      xsq0 = fmaf(a0v[j], a0v[j], xsq0);
      unsigned hb1 = f2bf(a1v[j]);
      ahi1[j] = (short)hb1;
      alo1[j] = (short)f2bf(a1v[j] - bf2f(hb1));
      xsq1 = fmaf(a1v[j], a1v[j], xsq1);
    }
    if (t < 15) {
      p00 = *(const float4*)(xrow0 + 32*(t+1));
      p01 = *(const float4*)(xrow0 + 32*(t+1) + 4);
      p10 = *(const float4*)(xrow1 + 32*(t+1));
      p11 = *(const float4*)(xrow1 + 32*(t+1) + 4);
    }
    #pragma unroll
    for (int s = 0; s < 8; ++s) {
      acc0[s] = __builtin_amdgcn_mfma_f32_16x16x32_bf16(ahi0, b[s], acc0[s], 0, 0, 0);
      acc0[s] = __builtin_amdgcn_mfma_f32_16x16x32_bf16(alo0, b[s], acc0[s], 0, 0, 0);
      acc1[s] = __builtin_amdgcn_mfma_f32_16x16x32_bf16(ahi1, b[s], acc1[s], 0, 0, 0);
      acc1[s] = __builtin_amdgcn_mfma_f32_16x16x32_bf16(alo1, b[s], acc1[s], 0, 0, 0);
    }
  }

  xsq0 += __shfl_xor(xsq0, 16, 64); xsq0 += __shfl_xor(xsq0, 32, 64);
  xsq1 += __shfl_xor(xsq1, 16, 64); xsq1 += __shfl_xor(xsq1, 32, 64);
  float xnv4[2][4], art4[2][4];
  #pragma unroll
  for (int i = 0; i < 4; ++i) {
    float s20 = __shfl(xsq0, 4*g + i, 64);
    float s21 = __shfl(xsq1, 4*g + i, 64);
    float xn0 = fmaxf(sqrtf(s20), 1e-15f);
    float xn1 = fmaxf(sqrtf(s21), 1e-15f);
    float aa0 = fminf(xn0, 1.f - 1e-7f);
    float aa1 = fminf(xn1, 1.f - 1e-7f);
    xnv4[0][i] = xn0; art4[0][i] = 0.5f * (log1pf(aa0) - log1pf(-aa0));
    xnv4[1][i] = xn1; art4[1][i] = 0.5f * (log1pf(aa1) - log1pf(-aa1));
  }

  float bl[8];
  #pragma unroll
  for (int s = 0; s < 8; ++s) bl[s] = bvec[16*(8*w+s) + l15];
  float m2p[2][4] = {{0.f,0.f,0.f,0.f},{0.f,0.f,0.f,0.f}};
  float mbp[2][4] = {{0.f,0.f,0.f,0.f},{0.f,0.f,0.f,0.f}};
  float b2p = 0.f;
  #pragma unroll
  for (int s = 0; s < 8; ++s) {
    b2p += bl[s]*bl[s];
    #pragma unroll
    for (int i = 0; i < 4; ++i) {
      m2p[0][i] = fmaf(acc0[s][i], acc0[s][i], m2p[0][i]);
      mbp[0][i] = fmaf(acc0[s][i], bl[s], mbp[0][i]);
      m2p[1][i] = fmaf(acc1[s][i], acc1[s][i], m2p[1][i]);
      mbp[1][i] = fmaf(acc1[s][i], bl[s], mbp[1][i]);
    }
  }
  #pragma unroll
  for (int off = 1; off <= 8; off <<= 1) {
    b2p += __shfl_xor(b2p, off, 64);
    #pragma unroll
    for (int rg = 0; rg < 2; ++rg)
      #pragma unroll
      for (int i = 0; i < 4; ++i) {
        m2p[rg][i] += __shfl_xor(m2p[rg][i], off, 64);
        mbp[rg][i] += __shfl_xor(mbp[rg][i], off, 64);
      }
  }
  if (l == 0) smb2[w] = b2p;
  if (l15 == 0) {
    #pragma unroll
    for (int rg = 0; rg < 2; ++rg)
      #pragma unroll
      for (int i = 0; i < 4; ++i) { smM[rg][w][g][i] = m2p[rg][i]; smB[rg][w][g][i] = mbp[rg][i]; }
  }
  __syncthreads();
  float b2 = smb2[0] + smb2[1] + smb2[2] + smb2[3];
  #pragma unroll
  for (int rg = 0; rg < 2; ++rg) {
    const f32x4* acc = rg ? acc1 : acc0;
    #pragma unroll
    for (int i = 0; i < 4; ++i) {
      float m2 = smM[rg][0][g][i]+smM[rg][1][g][i]+smM[rg][2][g][i]+smM[rg][3][g][i];
      float mb = smB[rg][0][g][i]+smB[rg][1][g][i]+smB[rg][2][g][i]+smB[rg][3][g][i];
      float xn = xnv4[rg][i], art = art4[rg][i];
      float mn = fmaxf(sqrtf(m2), 1e-15f);
      float t = tanhf(mn / xn * art);
      float alpha, rn;
      if (m2 > 0.f) { alpha = t / mn; rn = t; } else { alpha = 0.f; rn = 0.f; }
      if (rn > MAXN) { alpha *= MAXN / rn; rn = MAXN; }
      float x2r = rn * rn;
      float xy = alpha * mb;
      float A  = 1.f + 2.f*xy + b2;
      float Bc = 1.f - x2r;
      float den = fmaxf(1.f + 2.f*xy + x2r*b2, 1e-15f);
      float n2v = (A*A*x2r + 2.f*A*Bc*xy + Bc*Bc*b2) / (den*den);
      float nn = fmaxf(sqrtf(n2v), 1e-15f);
      float sc = (nn > MAXN) ? (MAXN / nn) : 1.f;
      float Gv = sc * A * alpha / den;
      float Hv = sc * Bc / den;
      int grow = R*32 + rg*16 + 4*g + i;
      #pragma unroll
      for (int s = 0; s < 8; ++s)
        outF[(size_t)grow*E_ + 16*(8*w+s) + l15] = Gv*acc[s][i] + Hv*bl[s];
    }
  }
}

// ---- Attention (r19-proven best): Kf+Vf double-buffered (40KB, 4 blocks/CU),
// one barrier per tile; softmax via precomputed rsqrt factors.
__global__ __launch_bounds__(256, 4) void attn_kernel(
    const unsigned short* __restrict__ Qhi, const unsigned short* __restrict__ Khi,
    const unsigned short* __restrict__ Vhi,
    const float* __restrict__ qn_arr, const float* __restrict__ kn_arr,
    const float* __restrict__ kni_arr, float* __restrict__ Out) {
  __shared__ __align__(16) unsigned short Kf[2][4096];
  __shared__ __align__(16) unsigned short Vf[2][4096];
  __shared__ __align__(16) unsigned short Pf[4][1024];   // 40KB total

  int tid = threadIdx.x;
  int w = tid >> 6, l = tid & 63;
  int l15 = l & 15, g = l >> 4;

  int bid = blockIdx.x;                 // XCD swizzle: xcd owns bh 4*xcd..4*xcd+3
  int xcd = bid & 7, idx = bid >> 3;
  int bh = xcd * 4 + (idx >> 5);
  int qblk = idx & 31;
  int b = bh >> 3, h = bh & 7;
  int qb = qblk * 64;

  const unsigned short* qbase = Qhi + ((size_t)(bh*32 + qblk))*4096;
  short8 qhi[2];
  #pragma unroll
  for (int dt = 0; dt < 2; ++dt)
    qhi[dt] = *(const short8*)(qbase + (size_t)((dt*4 + w)*64 + l)*8);
  float qnv[4], pr[4];
  #pragma unroll
  for (int i = 0; i < 4; ++i) {
    qnv[i] = qn_arr[(size_t)bh*S_ + qb + 16*w + 4*g + i];
    pr[i] = -0.25503386f * __builtin_amdgcn_rsqf(1.f - qnv[i]);
  }

  f32x4 Oacc[4];
  #pragma unroll
  for (int dn = 0; dn < 4; ++dn) Oacc[dn] = (f32x4){0.f,0.f,0.f,0.f};
  float lp[4] = {0.f,0.f,0.f,0.f};

  const unsigned short* Kbh = Khi + ((size_t)bh*32)*4096;
  const unsigned short* Vbh = Vhi + ((size_t)bh*32)*4096;
  const float* knp  = kn_arr  + (size_t)bh*S_;
  const float* knip = kni_arr + (size_t)bh*S_;

  #pragma unroll
  for (int r = 0; r < 2; ++r) {
    gload_lds16(Kbh + r*2048 + w*512 + l*8, &Kf[0][r*2048 + w*512]);
    gload_lds16(Vbh + r*2048 + w*512 + l*8, &Vf[0][r*2048 + w*512]);
  }
  asm volatile("s_waitcnt vmcnt(0)" ::: "memory");
  __syncthreads();

  #pragma unroll 1
  for (int tile = 0; tile < 32; ++tile) {
    int cur = tile & 1;
    int kb = tile * 64;
    float knc[4], kin[4];
    #pragma unroll
    for (int n = 0; n < 4; ++n) {       // issued first -> retire before stages
      knc[n] = knp[kb + 16*n + l15];
      kin[n] = knip[kb + 16*n + l15];
    }
    if (tile < 31) {
      const unsigned short* kp = Kbh + ((size_t)(tile+1))*4096;
      const unsigned short* vp = Vbh + ((size_t)(tile+1))*4096;
      #pragma unroll
      for (int r = 0; r < 2; ++r) {
        gload_lds16(kp + r*2048 + w*512 + l*8, &Kf[cur^1][r*2048 + w*512]);
        gload_lds16(vp + r*2048 + w*512 + l*8, &Vf[cur^1][r*2048 + w*512]);
      }
    }
    __builtin_amdgcn_sched_barrier(0);
    // ---- QK^T + softmax + P store
    #pragma unroll
    for (int n = 0; n < 4; ++n) {
      f32x4 Cn = (f32x4){0.f,0.f,0.f,0.f};
      #pragma unroll
      for (int dt = 0; dt < 2; ++dt) {
        short8 kfr = *(const short8*)&Kf[cur][((dt*4 + n)*64 + l)*8];
        Cn = __builtin_amdgcn_mfma_f32_16x16x32_bf16(qhi[dt], kfr, Cn, 0, 0, 0);
      }
      int cbase = (n >> 1)*64 + 16*((2*n + (l15 >> 3)) & 3) + 4*g;
      int csb = cbase ^ ((cbase >> 3) & 7);
      int j7 = l15 & 7;
      #pragma unroll
      for (int i = 0; i < 4; ++i) {
        float num = fmaf(-qnv[i], knc[n], Cn[i]);
        float d2 = fmaxf(num, 5e-6f);
        float sq = d2 * __builtin_amdgcn_rsqf(d2);             // sqrt(num)
        float p = __builtin_amdgcn_exp2f(pr[i] * kin[n] * sq); // exp(-dist/8)
        unsigned u = __float_as_uint(p);
        lp[i] += __uint_as_float(u & 0xffff0000u);
        Pf[w][((csb ^ i) << 3) + j7] = (unsigned short)(u >> 16);
      }
    }
    // ---- PV
    short8 pa0, pa1;
    { int c = l;       int cs = c ^ ((c >> 3) & 7); pa0 = *(const short8*)&Pf[w][cs*8]; }
    { int c = 64 + l;  int cs = c ^ ((c >> 3) & 7); pa1 = *(const short8*)&Pf[w][cs*8]; }
    #pragma unroll
    for (int dn = 0; dn < 4; ++dn) {
      short8 v0 = *(const short8*)&Vf[cur][((0*4 + dn)*64 + l)*8];
      short8 v1 = *(const short8*)&Vf[cur][((1*4 + dn)*64 + l)*8];
      f32x4 o = Oacc[dn];
      o = __builtin_amdgcn_mfma_f32_16x16x32_bf16(pa0, v0, o, 0, 0, 0);
      o = __builtin_amdgcn_mfma_f32_16x16x32_bf16(pa1, v1, o, 0, 0, 0);
      Oacc[dn] = o;
    }
    asm volatile("s_waitcnt vmcnt(0)" ::: "memory");
    __builtin_amdgcn_s_barrier();
  }

  #pragma unroll
  for (int i = 0; i < 4; ++i) {
    lp[i] += __shfl_xor(lp[i], 1, 64);
    lp[i] += __shfl_xor(lp[i], 2, 64);
    lp[i] += __shfl_xor(lp[i], 4, 64);
    lp[i] += __shfl_xor(lp[i], 8, 64);
    lp[i] = 1.f / lp[i];
  }
  #pragma unroll
  for (int i = 0; i < 4; ++i) {
    size_t orow = (size_t)(b*S_ + qb + 16*w + 4*g + i)*E_ + h*Dh_;
    #pragma unroll
    for (int dn = 0; dn < 4; ++dn)
      Out[orow + 16*dn + l15] = Oacc[dn][i] * lp[i];
  }
}

extern "C" void kernel_launch(void* const* d_in, const int* in_sizes, int n_in,
                              void* d_out, int out_size, void* d_ws, size_t ws_size,
                              hipStream_t stream) {
  const float* x  = (const float*)d_in[0];
  const float* Wq = (const float*)d_in[1];
  const float* bq = (const float*)d_in[2];
  const float* Wk = (const float*)d_in[3];
  const float* bk = (const float*)d_in[4];
  const float* Wv = (const float*)d_in[5];
  const float* bv = (const float*)d_in[6];
  const float* Wo = (const float*)d_in[7];
  const float* bo = (const float*)d_in[8];
  float* out = (float*)d_out;

  char* p = (char*)d_ws;
  unsigned short* Wp  = (unsigned short*)p; p += (size_t)2  << 20;  // 2 MB (hi only)
  unsigned short* Xp  = (unsigned short*)p; p += (size_t)17 << 20;  // 16.8 MB (hi+lo)
  unsigned short* Qhi = (unsigned short*)p; p += (size_t)8  << 20;
  unsigned short* Khi = (unsigned short*)p; p += (size_t)8  << 20;
  unsigned short* Vhi = (unsigned short*)p; p += (size_t)8  << 20;
  float* ao   = (float*)p; p += (size_t)16 << 20;                   // attn out fp32
  float* xn   = (float*)p; p += BS_ * 4;
  float* art  = (float*)p; p += BS_ * 4;
  float* qn   = (float*)p; p += (size_t)B_*H_*S_ * 4;
  float* kn   = (float*)p; p += (size_t)B_*H_*S_ * 4;
  float* kni  = (float*)p; p += (size_t)B_*H_*S_ * 4;
  // total ~= 60 MB

  pack_wx_kernel<<<dim3(128 + BS_/16), dim3(256), 0, stream>>>(
      Wq, Wk, Wv, Wo, Wp, x, Xp, xn, art);
  qkv_linear<<<dim3(BS_/32, 3), dim3(256), 0, stream>>>(Xp, Wp, bq, bk, bv,
                                                        Qhi, Khi, Vhi, xn, art, qn, kn, kni);
  attn_kernel<<<dim3(1024), dim3(256), 0, stream>>>(Qhi, Khi, Vhi, qn, kn, kni, ao);
  o_linear<<<dim3(BS_/32), dim3(256), 0, stream>>>(ao, Wp + 3*262144, bo, out);
}